// Round 10
// baseline (320.785 us; speedup 1.0000x reference)
//
#include <hip/hip_runtime.h>
#include <cstdint>
#include <cstddef>

typedef __bf16 bf16_t;
typedef bf16_t bf16x8 __attribute__((ext_vector_type(8)));
typedef float f32x4 __attribute__((ext_vector_type(4)));
typedef unsigned short u16x8 __attribute__((ext_vector_type(8)));
typedef unsigned short u16x4 __attribute__((ext_vector_type(4)));

#define SEQ 4096
#define BATCH 8
#define NTOK 32768      // BATCH*SEQ
#define NQKV 1536
#define DMODEL 512
#define NBH 64          // BATCH*HEADS
#define NCHUNK 8
#define KSTEPS 8        // both GEMMs have K=512 = 8 x 64

__device__ __forceinline__ unsigned short f2b(float f) {
    union { float f; unsigned u; } c; c.f = f;
    unsigned u = c.u;
    u += 0x7fffu + ((u >> 16) & 1u);   // round-to-nearest-even
    return (unsigned short)(u >> 16);
}
__device__ __forceinline__ float b2f(unsigned short h) {
    union { unsigned u; float f; } c; c.u = ((unsigned)h) << 16;
    return c.f;
}
__device__ __forceinline__ float feat(float v) {   // elu(v)+1
    return v > 0.f ? v + 1.f : __expf(v);
}

// async global->LDS, 16B per lane; LDS dest is wave-uniform base + lane*16
__device__ __forceinline__ void gload16(const unsigned short* g, unsigned short* lds_base) {
    __builtin_amdgcn_global_load_lds((const __attribute__((address_space(1))) unsigned int*)g,
                                     (__attribute__((address_space(3))) unsigned int*)lds_base,
                                     16, 0, 0);
}

// pack weight [Nw][512] fp32 -> MFMA-fragment-packed bf16:
// off = bcol*65536 + kt*8192 + wn*4096 + kk*2048 + ni*512 + lane*8
// n = bcol*128+wn*64+ni*16+(lane&15), k = kt*64+kk*32+(lane>>4)*8+ke
__device__ __forceinline__ void packW(const float* __restrict__ src,
                                      unsigned short* __restrict__ dst,
                                      int totalP4, int t0, int stride) {
    for (int j4 = t0; j4 < totalP4; j4 += stride) {
        int p = j4 << 2;
        int ke   = p & 7;              // 0 or 4
        int lane = (p >> 3) & 63;
        int ni   = (p >> 9) & 3;
        int kk   = (p >> 11) & 1;
        int wn   = (p >> 12) & 1;
        int kt   = (p >> 13) & 7;
        int bcol = p >> 16;
        int n = bcol * 128 + wn * 64 + ni * 16 + (lane & 15);
        int k = kt * 64 + kk * 32 + (lane >> 4) * 8 + ke;
        f32x4 v = *(const f32x4*)&src[(size_t)n * 512 + k];
        u16x4 o = { f2b(v[0]), f2b(v[1]), f2b(v[2]), f2b(v[3]) };
        ((u16x4*)dst)[j4] = o;
    }
}

// ---------------- prep: x -> bf16; weights -> fragment-packed bf16 ----------------
__global__ __launch_bounds__(256) void prep_kernel(const float* __restrict__ x,
                                                   const float* __restrict__ wqkv,
                                                   const float* __restrict__ wout,
                                                   unsigned short* __restrict__ xB,
                                                   unsigned short* __restrict__ wqkvP,
                                                   unsigned short* __restrict__ woutP) {
    const int stride = gridDim.x * 256;
    const int t0 = blockIdx.x * 256 + threadIdx.x;
    for (int j = t0; j < NTOK * DMODEL / 4; j += stride) {
        f32x4 v = ((const f32x4*)x)[j];
        u16x4 o = { f2b(v[0]), f2b(v[1]), f2b(v[2]), f2b(v[3]) };
        ((u16x4*)xB)[j] = o;
    }
    packW(wqkv, wqkvP, NQKV * DMODEL / 4, t0, stride);
    packW(wout, woutP, DMODEL * DMODEL / 4, t0, stride);
}

// ---------------- MFMA GEMM: C = A @ B^T, A bf16 [M][512], B fragment-packed ----------------
// Barrier-free A-resident structure: block = 128 rows x ALL columns.
// A[128][512] staged ONCE into LDS (128 KiB, XOR-swizzled via pre-swizzled source),
// ONE __syncthreads, then 96-step loop (nPanels x 8 kt) with zero barriers:
// A frags from static LDS, B frags from packed L2 (R9-proven), per-panel epilogue.
// 8 waves = 2M x 4N over each 128x128 panel (wave = 64 rows x 32 cols, acc[4][2]).
// MODE 0: feature-map epilogue -> qF [tok][512] bf16; kT/vT [bh][d][4096] bf16 (transposed)
// MODE 1: +bias epilogue -> fp32 out [tok][512]   (Ck/Cv unused)
template <int MODE>
__global__ __launch_bounds__(512) void gemm_kernel(const unsigned short* __restrict__ A,
                                                   const unsigned short* __restrict__ Bp,
                                                   void* __restrict__ Cq,
                                                   unsigned short* __restrict__ Ck,
                                                   unsigned short* __restrict__ Cv,
                                                   const float* __restrict__ bias,
                                                   int K, int nPanels) {
    __shared__ __align__(16) unsigned short As_[128 * 512];   // 128 KiB, staged once
    const int tid = threadIdx.x;
    const int nwg = gridDim.x;
    int bid = blockIdx.x;
    if ((nwg & 7) == 0) bid = (bid & 7) * (nwg >> 3) + (bid >> 3);
    const int rowBase = bid * 128;
    const int lane = tid & 63, wv = tid >> 6;      // 8 waves
    const int wm = wv >> 2, wc = wv & 3;           // 2M x 4N; wave = 64 rows x 32 cols
    const int wn = wc >> 1;                        // 64-col half within panel
    const int nodd = wc & 1;                       // which pair of 16-col frags
    const int lr = lane & 15, lk = lane >> 4;

    // ---- one-time stage of A[128][512]: 16 rounds, 8 rows each ----
    // LDS linear: byte = row*1024 + lane*16 ; source col slot XOR-swizzled so that
    // read addr = row*1024 + ((kt*128 + kk*64 + lk*16) ^ ((row&7)<<4)) is conflict-free.
    #pragma unroll
    for (int j = 0; j < 16; ++j) {
        int row = j * 8 + wv;
        int slot = (lane & 56) | ((lane & 7) ^ (row & 7));
        gload16(A + (size_t)(rowBase + row) * K + slot * 8, As_ + row * 512 + lane * 8);
    }
    __syncthreads();                               // the ONLY barrier

    for (int panel = 0; panel < nPanels; ++panel) {
        const unsigned short* bpp = Bp + ((size_t)panel << 16) + (wn << 12) + ((nodd * 2) << 9) + (lane << 3);
        f32x4 acc[4][2] = {};
        #pragma unroll
        for (int kt = 0; kt < KSTEPS; ++kt) {
            bf16x8 bfr[2][2];
            #pragma unroll
            for (int kk = 0; kk < 2; ++kk)
                #pragma unroll
                for (int nj = 0; nj < 2; ++nj)
                    bfr[kk][nj] = *(const bf16x8*)(bpp + (kt << 13) + (kk << 11) + (nj << 9));
            #pragma unroll
            for (int kk = 0; kk < 2; ++kk) {
                bf16x8 af[4];
                #pragma unroll
                for (int mi = 0; mi < 4; ++mi) {
                    int row = wm * 64 + mi * 16 + lr;
                    af[mi] = *(const bf16x8*)((const char*)As_ + row * 1024 +
                                              ((kt * 128 + kk * 64 + lk * 16) ^ ((row & 7) << 4)));
                }
                #pragma unroll
                for (int mi = 0; mi < 4; ++mi)
                    #pragma unroll
                    for (int nj = 0; nj < 2; ++nj)
                        acc[mi][nj] = __builtin_amdgcn_mfma_f32_16x16x32_bf16(af[mi], bfr[kk][nj], acc[mi][nj], 0, 0, 0);
            }
        }

        // ---- per-panel epilogue: C/D layout col=lane&15, row=(lane>>4)*4+reg ----
        const int colBase = panel * 128;
        if (MODE == 1) {
            #pragma unroll
            for (int mi = 0; mi < 4; ++mi) {
                const int grow0 = rowBase + wm * 64 + mi * 16 + lk * 4;
                #pragma unroll
                for (int nj = 0; nj < 2; ++nj) {
                    const int gcol = colBase + wn * 64 + (nodd * 2 + nj) * 16 + lr;
                    #pragma unroll
                    for (int r = 0; r < 4; ++r)
                        ((float*)Cq)[(size_t)(grow0 + r) * DMODEL + gcol] = acc[mi][nj][r] + bias[gcol];
                }
            }
        } else if (colBase < 512) {           // q: elu(q*scale)+1, row-major [tok][512]
            #pragma unroll
            for (int mi = 0; mi < 4; ++mi) {
                const int grow0 = rowBase + wm * 64 + mi * 16 + lk * 4;
                #pragma unroll
                for (int nj = 0; nj < 2; ++nj) {
                    const int gcol = colBase + wn * 64 + (nodd * 2 + nj) * 16 + lr;
                    #pragma unroll
                    for (int r = 0; r < 4; ++r)
                        ((unsigned short*)Cq)[(size_t)(grow0 + r) * DMODEL + gcol] =
                            f2b(feat(acc[mi][nj][r] * 0.125f));
                }
            }
        } else if (colBase < 1024) {          // k: elu(k)+1 -> kT [bh*64+d][n]
            #pragma unroll
            for (int mi = 0; mi < 4; ++mi) {
                const int grow0 = rowBase + wm * 64 + mi * 16 + lk * 4;
                const int b_ = grow0 >> 12, n0 = grow0 & 4095;
                #pragma unroll
                for (int nj = 0; nj < 2; ++nj) {
                    const int hd = colBase - 512 + wn * 64 + (nodd * 2 + nj) * 16 + lr;
                    u16x4 o = { f2b(feat(acc[mi][nj][0])), f2b(feat(acc[mi][nj][1])),
                                f2b(feat(acc[mi][nj][2])), f2b(feat(acc[mi][nj][3])) };
                    *(u16x4*)&Ck[((size_t)(b_ * 512 + hd)) * SEQ + n0] = o;
                }
            }
        } else {                              // v raw -> vT [bh*64+d][n]
            #pragma unroll
            for (int mi = 0; mi < 4; ++mi) {
                const int grow0 = rowBase + wm * 64 + mi * 16 + lk * 4;
                const int b_ = grow0 >> 12, n0 = grow0 & 4095;
                #pragma unroll
                for (int nj = 0; nj < 2; ++nj) {
                    const int hd = colBase - 1024 + wn * 64 + (nodd * 2 + nj) * 16 + lr;
                    u16x4 o = { f2b(acc[mi][nj][0]), f2b(acc[mi][nj][1]),
                                f2b(acc[mi][nj][2]), f2b(acc[mi][nj][3]) };
                    *(u16x4*)&Cv[((size_t)(b_ * 512 + hd)) * SEQ + n0] = o;
                }
            }
        }
    }
}

// ---------------- ctx (MFMA): ctxP[chunk][bh][d][e] = sum_n k[n][d] v[n][e]; kc via ones ----
__global__ __launch_bounds__(256) void ctx_kernel(const unsigned short* __restrict__ kT,
                                                  const unsigned short* __restrict__ vT,
                                                  float* __restrict__ ctxP,
                                                  float* __restrict__ kcP) {
    const int bh = blockIdx.x >> 3;
    const int chunk = blockIdx.x & 7;
    __shared__ __align__(16) unsigned short ks[64 * 64];
    __shared__ __align__(16) unsigned short vs[64 * 64];
    const int tid = threadIdx.x;
    const int lane = tid & 63, wv = tid >> 6;
    const int lr = lane & 15, lk = lane >> 4;
    const int xorv = (lr & 7) << 4;
    const int r_s = tid >> 3, s_s = tid & 7;
    const unsigned short* kg = kT + (size_t)bh * 64 * SEQ;
    const unsigned short* vg = vT + (size_t)bh * 64 * SEQ;

    f32x4 acc[4] = {};
    f32x4 kacc[4] = {};
    union { u16x8 u; bf16x8 b; } onesc;
    onesc.u = (u16x8){0x3F80, 0x3F80, 0x3F80, 0x3F80, 0x3F80, 0x3F80, 0x3F80, 0x3F80};
    const bf16x8 ones = onesc.b;

    for (int t = 0; t < 8; ++t) {
        const int n0 = chunk * 512 + t * 64;
        __syncthreads();                                  // protect prev-tile reads
        #pragma unroll
        for (int j = 0; j < 2; ++j) {
            int r = j * 32 + r_s;                         // d-row 0..63
            int scol = ((s_s ^ (r & 7)) << 3) + n0;       // pre-swizzled source
            gload16(kg + (size_t)r * SEQ + scol, ks + (j * 256 + (wv << 6)) * 8);
            gload16(vg + (size_t)r * SEQ + scol, vs + (j * 256 + (wv << 6)) * 8);
        }
        __syncthreads();                                  // drain gload16
        #pragma unroll
        for (int kk = 0; kk < 2; ++kk) {
            bf16x8 bfr = *(const bf16x8*)((const char*)vs + (wv * 16 + lr) * 128 + ((kk * 64 + lk * 16) ^ xorv));
            #pragma unroll
            for (int mi = 0; mi < 4; ++mi) {
                bf16x8 af = *(const bf16x8*)((const char*)ks + (mi * 16 + lr) * 128 + ((kk * 64 + lk * 16) ^ xorv));
                acc[mi] = __builtin_amdgcn_mfma_f32_16x16x32_bf16(af, bfr, acc[mi], 0, 0, 0);
                if (wv == 0)
                    kacc[mi] = __builtin_amdgcn_mfma_f32_16x16x32_bf16(af, ones, kacc[mi], 0, 0, 0);
            }
        }
    }
    float* cp = ctxP + ((size_t)chunk * NBH + bh) * 4096;
    #pragma unroll
    for (int mi = 0; mi < 4; ++mi)
        #pragma unroll
        for (int r = 0; r < 4; ++r)
            cp[(mi * 16 + lk * 4 + r) * 64 + wv * 16 + lr] = acc[mi][r];
    if (wv == 0 && lr == 0) {
        float* kp = kcP + ((size_t)chunk * NBH + bh) * 64;
        #pragma unroll
        for (int mi = 0; mi < 4; ++mi)
            #pragma unroll
            for (int r = 0; r < 4; ++r)
                kp[mi * 16 + lk * 4 + r] = kacc[mi][r];
    }
}

// ---------------- reduce: sum partials; emit ctxT hi/lo bf16 [bh][e][d] + kc fp32 ----------------
__global__ __launch_bounds__(256) void reduce_kernel(const float* __restrict__ ctxP,
                                                     const float* __restrict__ kcP,
                                                     unsigned short* __restrict__ cTh,
                                                     unsigned short* __restrict__ cTl,
                                                     float* __restrict__ kcR) {
    const int bh = blockIdx.x;
    const int t = threadIdx.x;
    #pragma unroll
    for (int p = 0; p < 4; ++p) {
        int idx = p * 256 + t;                            // f32x4 index; elems [d][e0..e0+3]
        f32x4 s = {0.f, 0.f, 0.f, 0.f};
        for (int c = 0; c < NCHUNK; ++c)
            s += ((const f32x4*)(ctxP + ((size_t)c * NBH + bh) * 4096))[idx];
        int d = idx >> 4, e0 = (idx & 15) * 4;
        #pragma unroll
        for (int j = 0; j < 4; ++j) {
            unsigned short hi = f2b(s[j]);
            cTh[(size_t)bh * 4096 + (e0 + j) * 64 + d] = hi;
            cTl[(size_t)bh * 4096 + (e0 + j) * 64 + d] = f2b(s[j] - b2f(hi));
        }
    }
    if (t < 64) {
        float s = 0.f;
        for (int c = 0; c < NCHUNK; ++c) s += kcP[((size_t)c * NBH + bh) * 64 + t];
        kcR[bh * 64 + t] = s;
    }
}

// ---------------- attn (MFMA): inner[n][h*64+e] = (q @ (ctx_hi+ctx_lo)) / (q . kc) ----------------
__global__ __launch_bounds__(256) void attn_kernel(const unsigned short* __restrict__ qF,
                                                   const unsigned short* __restrict__ cTh,
                                                   const unsigned short* __restrict__ cTl,
                                                   const float* __restrict__ kcR,
                                                   unsigned short* __restrict__ inner) {
    const int bh = blockIdx.x >> 6;
    const int rt = blockIdx.x & 63;
    const int b = bh >> 3, h = bh & 7;
    const size_t rowBase = (size_t)b * SEQ + (size_t)rt * 64;
    __shared__ __align__(16) unsigned short qs[64 * 64];
    __shared__ __align__(16) unsigned short chs[64 * 64];
    __shared__ __align__(16) unsigned short cls[64 * 64];
    __shared__ float dpart[64][4];
    __shared__ float dens[64];
    __shared__ float kcs[64];
    const int tid = threadIdx.x;
    const int lane = tid & 63, wv = tid >> 6;
    const int lr = lane & 15, lk = lane >> 4;
    const int xorv = (lr & 7) << 4;
    const int r_s = tid >> 3, s_s = tid & 7;

    #pragma unroll
    for (int j = 0; j < 2; ++j) {
        int r = j * 32 + r_s;
        int sc = (s_s ^ (r & 7)) << 3;
        gload16(qF + (rowBase + r) * DMODEL + h * 64 + sc, qs + (j * 256 + (wv << 6)) * 8);
        gload16(cTh + (size_t)bh * 4096 + r * 64 + sc, chs + (j * 256 + (wv << 6)) * 8);
        gload16(cTl + (size_t)bh * 4096 + r * 64 + sc, cls + (j * 256 + (wv << 6)) * 8);
    }
    if (tid < 64) kcs[tid] = kcR[bh * 64 + tid];
    __syncthreads();                                      // drain gload16 + kcs
    {   // denom partials: 4 d-quarters x 64 rows in parallel
        int row = tid & 63, part = tid >> 6;
        float s = 0.f;
        #pragma unroll
        for (int i = 0; i < 16; ++i) {
            int d = part * 16 + i;
            unsigned short qv = *(const unsigned short*)((const char*)qs + row * 128 + ((d * 2) ^ ((row & 7) << 4)));
            s += b2f(qv) * kcs[d];
        }
        dpart[row][part] = s;
    }
    __syncthreads();
    if (tid < 64) dens[tid] = 1e-8f + dpart[tid][0] + dpart[tid][1] + dpart[tid][2] + dpart[tid][3];
    __syncthreads();

    f32x4 acc[4] = {};
    #pragma unroll
    for (int kk = 0; kk < 2; ++kk) {
        bf16x8 af = *(const bf16x8*)((const char*)qs + (wv * 16 + lr) * 128 + ((kk * 64 + lk * 16) ^ xorv));
        #pragma unroll
        for (int ni = 0; ni < 4; ++ni) {
            bf16x8 bh_ = *(const bf16x8*)((const char*)chs + (ni * 16 + lr) * 128 + ((kk * 64 + lk * 16) ^ xorv));
            bf16x8 bl_ = *(const bf16x8*)((const char*)cls + (ni * 16 + lr) * 128 + ((kk * 64 + lk * 16) ^ xorv));
            acc[ni] = __builtin_amdgcn_mfma_f32_16x16x32_bf16(af, bh_, acc[ni], 0, 0, 0);
            acc[ni] = __builtin_amdgcn_mfma_f32_16x16x32_bf16(af, bl_, acc[ni], 0, 0, 0);
        }
    }
    #pragma unroll
    for (int ni = 0; ni < 4; ++ni)
        #pragma unroll
        for (int r = 0; r < 4; ++r) {
            int n = wv * 16 + lk * 4 + r;
            float o = acc[ni][r] / dens[n];
            inner[(rowBase + n) * DMODEL + h * 64 + ni * 16 + lr] = f2b(o);
        }
}

extern "C" void kernel_launch(void* const* d_in, const int* in_sizes, int n_in,
                              void* d_out, int out_size, void* d_ws, size_t ws_size,
                              hipStream_t stream) {
    (void)in_sizes; (void)n_in; (void)out_size; (void)ws_size;
    const float* x    = (const float*)d_in[0];
    const float* wqkv = (const float*)d_in[1];
    const float* wout = (const float*)d_in[2];
    const float* bout = (const float*)d_in[3];

    char* w = (char*)d_ws;
    // Region [0, 32MB): xB (prep->gemm0), then ctxP+kcP (ctx->reduce), then inner (attn->gemm1)
    unsigned short* xB    = (unsigned short*)(w);                 // 32768*512*2  = 33554432
    float*          ctxP  = (float*)(w);                          // 8*64*4096*4  = 8388608
    float*          kcP   = (float*)(w + 8388608);                // 8*64*64*4    = 131072
    unsigned short* inner = (unsigned short*)(w);                 // 33554432
    unsigned short* qF    = (unsigned short*)(w + 33554432);      // 32768*512*2  = 33554432
    unsigned short* kT    = (unsigned short*)(w + 67108864);      // 64*64*4096*2 = 33554432
    unsigned short* vT    = (unsigned short*)(w + 100663296);     // 33554432
    unsigned short* wqkvP = (unsigned short*)(w + 134217728);     // 1536*512*2 = 1572864 (packed)
    unsigned short* woutP = (unsigned short*)(w + 135790592);     // 512*512*2  = 524288  (packed)
    unsigned short* cTh   = (unsigned short*)(w + 136314880);     // 64*64*64*2   = 524288
    unsigned short* cTl   = (unsigned short*)(w + 136839168);     // 524288
    float*          kcR   = (float*)(w + 137363456);              // 64*64*4      = 16384
    // total ws usage: 137379840 bytes (< 144834560 proven available)

    hipLaunchKernelGGL(prep_kernel, dim3(2048), dim3(256), 0, stream,
                       x, wqkv, wout, xB, wqkvP, woutP);
    hipLaunchKernelGGL((gemm_kernel<0>), dim3(256), dim3(512), 0, stream,
                       xB, wqkvP, (void*)qF, kT, vT, (const float*)nullptr,
                       DMODEL, 12);
    hipLaunchKernelGGL(ctx_kernel, dim3(NBH * NCHUNK), dim3(256), 0, stream, kT, vT, ctxP, kcP);
    hipLaunchKernelGGL(reduce_kernel, dim3(NBH), dim3(256), 0, stream, ctxP, kcP, cTh, cTl, kcR);
    hipLaunchKernelGGL(attn_kernel, dim3(NBH * 64), dim3(256), 0, stream, qF, cTh, cTl, kcR, inner);
    hipLaunchKernelGGL((gemm_kernel<1>), dim3(256), dim3(512), 0, stream,
                       inner, woutP, (void*)d_out, (unsigned short*)nullptr, (unsigned short*)nullptr, bout,
                       DMODEL, 4);
}

// Round 11
// 159.345 us; speedup vs baseline: 2.0131x; 2.0131x over previous
//
#include <hip/hip_runtime.h>
#include <cstdint>
#include <cstddef>

typedef __bf16 bf16_t;
typedef bf16_t bf16x8 __attribute__((ext_vector_type(8)));
typedef float f32x4 __attribute__((ext_vector_type(4)));
typedef unsigned short u16x8 __attribute__((ext_vector_type(8)));
typedef unsigned short u16x4 __attribute__((ext_vector_type(4)));

#define SEQ 4096
#define BATCH 8
#define NTOK 32768      // BATCH*SEQ
#define NQKV 1536
#define DMODEL 512
#define NBH 64          // BATCH*HEADS
#define NCHUNK 8

__device__ __forceinline__ unsigned short f2b(float f) {
    union { float f; unsigned u; } c; c.f = f;
    unsigned u = c.u;
    u += 0x7fffu + ((u >> 16) & 1u);   // round-to-nearest-even
    return (unsigned short)(u >> 16);
}
__device__ __forceinline__ float b2f(unsigned short h) {
    union { unsigned u; float f; } c; c.u = ((unsigned)h) << 16;
    return c.f;
}
__device__ __forceinline__ float feat(float v) {   // elu(v)+1
    return v > 0.f ? v + 1.f : __expf(v);
}

// async global->LDS, 16B per lane; LDS dest is wave-uniform base + lane*16
__device__ __forceinline__ void gload16(const unsigned short* g, unsigned short* lds_base) {
    __builtin_amdgcn_global_load_lds((const __attribute__((address_space(1))) unsigned int*)g,
                                     (__attribute__((address_space(3))) unsigned int*)lds_base,
                                     16, 0, 0);
}

// ---------------- prep: fp32 -> bf16 for x and both weights ----------------
__global__ __launch_bounds__(256) void prep_kernel(const float* __restrict__ x,
                                                   const float* __restrict__ wqkv,
                                                   const float* __restrict__ wout,
                                                   unsigned short* __restrict__ xB,
                                                   unsigned short* __restrict__ wqkvB,
                                                   unsigned short* __restrict__ woutB) {
    const int stride = gridDim.x * 256;
    const int t0 = blockIdx.x * 256 + threadIdx.x;
    for (int j = t0; j < NTOK * DMODEL / 4; j += stride) {
        f32x4 v = ((const f32x4*)x)[j];
        u16x4 o = { f2b(v[0]), f2b(v[1]), f2b(v[2]), f2b(v[3]) };
        ((u16x4*)xB)[j] = o;
    }
    for (int j = t0; j < NQKV * DMODEL / 4; j += stride) {
        f32x4 v = ((const f32x4*)wqkv)[j];
        u16x4 o = { f2b(v[0]), f2b(v[1]), f2b(v[2]), f2b(v[3]) };
        ((u16x4*)wqkvB)[j] = o;
    }
    for (int j = t0; j < DMODEL * DMODEL / 4; j += stride) {
        f32x4 v = ((const f32x4*)wout)[j];
        u16x4 o = { f2b(v[0]), f2b(v[1]), f2b(v[2]), f2b(v[3]) };
        ((u16x4*)woutB)[j] = o;
    }
}

// ---------------- MFMA GEMM: C = A @ B^T, A bf16 [M][K], B bf16 [N][K] ----------------
// 256x256 tile, 8 waves (4M x 2N; wave = 64 rows x 128 cols, acc[4][8]), BK=64.
// R7-proven rhythm: single-buffer LDS (A 32K + B 32K), two __syncthreads per step,
// gload16 staging + T2 XOR-swizzle (0 conflicts), T1 XCD swizzle.
// Halves cache-read traffic vs 256x128 (A re-read 12->6x) -- the R7-R9 plateau theory.
// MODE 0: feature-map epilogue -> qF [tok][512] bf16; kT/vT [bh][d][4096] bf16 (transposed)
// MODE 1: +bias epilogue -> fp32 out [tok][512]   (Ck/Cv unused)
template <int MODE>
__global__ __launch_bounds__(512) void gemm_kernel(const unsigned short* __restrict__ A,
                                                   const unsigned short* __restrict__ B,
                                                   void* __restrict__ Cq,
                                                   unsigned short* __restrict__ Ck,
                                                   unsigned short* __restrict__ Cv,
                                                   const float* __restrict__ bias,
                                                   int M, int N, int K, int nColBlocks) {
    __shared__ __align__(16) unsigned short As_[256 * 64];   // 32 KiB
    __shared__ __align__(16) unsigned short Bs_[256 * 64];   // 32 KiB
    const int tid = threadIdx.x;
    const int nwg = gridDim.x;
    int bid = blockIdx.x;
    if ((nwg & 7) == 0) bid = (bid & 7) * (nwg >> 3) + (bid >> 3);
    const int brow = bid / nColBlocks, bcol = bid % nColBlocks;
    const int rowBase = brow * 256, colBase = bcol * 256;
    const int lane = tid & 63, wv = tid >> 6;      // 8 waves
    const int wm = wv >> 1, wn = wv & 1;           // 4M x 2N (wave = 64 x 128 output)
    const int lr = lane & 15, lk = lane >> 4;
    const int xorv_rd = 0;                         // (read xor applied per-row below)
    const int sr = tid >> 3;                       // staging row within 64-row round
    const int ss = tid & 7;                        // staging slot

    f32x4 acc[4][8] = {};

    for (int kt = 0; kt < K; kt += 64) {
        // ---- stage A 256x64 (4 rounds) + B 256x64 (4 rounds), pre-swizzled source ----
        #pragma unroll
        for (int j = 0; j < 4; ++j) {
            int r = j * 64 + sr;
            int scol = ((ss ^ (r & 7)) << 3) + kt;
            gload16(A + (size_t)(rowBase + r) * K + scol, As_ + (j * 64 + (wv << 3)) * 64);
        }
        #pragma unroll
        for (int j = 0; j < 4; ++j) {
            int r = j * 64 + sr;
            int scol = ((ss ^ (r & 7)) << 3) + kt;
            gload16(B + (size_t)(colBase + r) * K + scol, Bs_ + (j * 64 + (wv << 3)) * 64);
        }
        __syncthreads();   // vmcnt(0) drain at barrier
        #pragma unroll
        for (int kk = 0; kk < 2; ++kk) {
            bf16x8 af[4], bfr[8];
            #pragma unroll
            for (int mi = 0; mi < 4; ++mi) {
                int row = wm * 64 + mi * 16 + lr;
                af[mi] = *(const bf16x8*)((const char*)As_ + row * 128 +
                                          ((kk * 64 + lk * 16) ^ ((row & 7) << 4)));
            }
            #pragma unroll
            for (int nj = 0; nj < 8; ++nj) {
                int row = wn * 128 + nj * 16 + lr;
                bfr[nj] = *(const bf16x8*)((const char*)Bs_ + row * 128 +
                                           ((kk * 64 + lk * 16) ^ ((row & 7) << 4)));
            }
            #pragma unroll
            for (int mi = 0; mi < 4; ++mi)
                #pragma unroll
                for (int nj = 0; nj < 8; ++nj)
                    acc[mi][nj] = __builtin_amdgcn_mfma_f32_16x16x32_bf16(af[mi], bfr[nj], acc[mi][nj], 0, 0, 0);
        }
        __syncthreads();   // protect LDS before next-step staging
    }
    (void)xorv_rd;

    // ---- epilogue: C/D layout col=lane&15, row=(lane>>4)*4+reg ----
    // segment uniform per (block, wn): 256-col blocks never straddle q/k/v boundaries.
    const int colSeg = colBase + wn * 128;
    if (MODE == 1) {
        #pragma unroll
        for (int mi = 0; mi < 4; ++mi) {
            const int grow0 = rowBase + wm * 64 + mi * 16 + lk * 4;
            #pragma unroll
            for (int nj = 0; nj < 8; ++nj) {
                const int gcol = colSeg + nj * 16 + lr;
                #pragma unroll
                for (int r = 0; r < 4; ++r)
                    ((float*)Cq)[(size_t)(grow0 + r) * DMODEL + gcol] = acc[mi][nj][r] + bias[gcol];
            }
        }
    } else if (colSeg < 512) {            // q: elu(q*scale)+1, row-major [tok][512]
        #pragma unroll
        for (int mi = 0; mi < 4; ++mi) {
            const int grow0 = rowBase + wm * 64 + mi * 16 + lk * 4;
            #pragma unroll
            for (int nj = 0; nj < 8; ++nj) {
                const int gcol = colSeg + nj * 16 + lr;
                #pragma unroll
                for (int r = 0; r < 4; ++r)
                    ((unsigned short*)Cq)[(size_t)(grow0 + r) * DMODEL + gcol] =
                        f2b(feat(acc[mi][nj][r] * 0.125f));
            }
        }
    } else if (colSeg < 1024) {           // k: elu(k)+1 -> kT [bh*64+d][n]
        #pragma unroll
        for (int mi = 0; mi < 4; ++mi) {
            const int grow0 = rowBase + wm * 64 + mi * 16 + lk * 4;
            const int b_ = grow0 >> 12, n0 = grow0 & 4095;
            #pragma unroll
            for (int nj = 0; nj < 8; ++nj) {
                const int hd = colSeg - 512 + nj * 16 + lr;
                u16x4 o = { f2b(feat(acc[mi][nj][0])), f2b(feat(acc[mi][nj][1])),
                            f2b(feat(acc[mi][nj][2])), f2b(feat(acc[mi][nj][3])) };
                *(u16x4*)&Ck[((size_t)(b_ * 512 + hd)) * SEQ + n0] = o;
            }
        }
    } else {                              // v raw -> vT [bh*64+d][n]
        #pragma unroll
        for (int mi = 0; mi < 4; ++mi) {
            const int grow0 = rowBase + wm * 64 + mi * 16 + lk * 4;
            const int b_ = grow0 >> 12, n0 = grow0 & 4095;
            #pragma unroll
            for (int nj = 0; nj < 8; ++nj) {
                const int hd = colSeg - 1024 + nj * 16 + lr;
                u16x4 o = { f2b(acc[mi][nj][0]), f2b(acc[mi][nj][1]),
                            f2b(acc[mi][nj][2]), f2b(acc[mi][nj][3]) };
                *(u16x4*)&Cv[((size_t)(b_ * 512 + hd)) * SEQ + n0] = o;
            }
        }
    }
}

// ---------------- ctx (MFMA): ctxP[chunk][bh][d][e] = sum_n k[n][d] v[n][e]; kc via ones ----
__global__ __launch_bounds__(256) void ctx_kernel(const unsigned short* __restrict__ kT,
                                                  const unsigned short* __restrict__ vT,
                                                  float* __restrict__ ctxP,
                                                  float* __restrict__ kcP) {
    const int bh = blockIdx.x >> 3;
    const int chunk = blockIdx.x & 7;
    __shared__ __align__(16) unsigned short ks[64 * 64];
    __shared__ __align__(16) unsigned short vs[64 * 64];
    const int tid = threadIdx.x;
    const int lane = tid & 63, wv = tid >> 6;
    const int lr = lane & 15, lk = lane >> 4;
    const int xorv = (lr & 7) << 4;
    const int r_s = tid >> 3, s_s = tid & 7;
    const unsigned short* kg = kT + (size_t)bh * 64 * SEQ;
    const unsigned short* vg = vT + (size_t)bh * 64 * SEQ;

    f32x4 acc[4] = {};
    f32x4 kacc[4] = {};
    union { u16x8 u; bf16x8 b; } onesc;
    onesc.u = (u16x8){0x3F80, 0x3F80, 0x3F80, 0x3F80, 0x3F80, 0x3F80, 0x3F80, 0x3F80};
    const bf16x8 ones = onesc.b;

    for (int t = 0; t < 8; ++t) {
        const int n0 = chunk * 512 + t * 64;
        __syncthreads();                                  // protect prev-tile reads
        #pragma unroll
        for (int j = 0; j < 2; ++j) {
            int r = j * 32 + r_s;                         // d-row 0..63
            int scol = ((s_s ^ (r & 7)) << 3) + n0;       // pre-swizzled source
            gload16(kg + (size_t)r * SEQ + scol, ks + (j * 256 + (wv << 6)) * 8);
            gload16(vg + (size_t)r * SEQ + scol, vs + (j * 256 + (wv << 6)) * 8);
        }
        __syncthreads();                                  // drain gload16
        #pragma unroll
        for (int kk = 0; kk < 2; ++kk) {
            bf16x8 bfr = *(const bf16x8*)((const char*)vs + (wv * 16 + lr) * 128 + ((kk * 64 + lk * 16) ^ xorv));
            #pragma unroll
            for (int mi = 0; mi < 4; ++mi) {
                bf16x8 af = *(const bf16x8*)((const char*)ks + (mi * 16 + lr) * 128 + ((kk * 64 + lk * 16) ^ xorv));
                acc[mi] = __builtin_amdgcn_mfma_f32_16x16x32_bf16(af, bfr, acc[mi], 0, 0, 0);
                if (wv == 0)
                    kacc[mi] = __builtin_amdgcn_mfma_f32_16x16x32_bf16(af, ones, kacc[mi], 0, 0, 0);
            }
        }
    }
    float* cp = ctxP + ((size_t)chunk * NBH + bh) * 4096;
    #pragma unroll
    for (int mi = 0; mi < 4; ++mi)
        #pragma unroll
        for (int r = 0; r < 4; ++r)
            cp[(mi * 16 + lk * 4 + r) * 64 + wv * 16 + lr] = acc[mi][r];
    if (wv == 0 && lr == 0) {
        float* kp = kcP + ((size_t)chunk * NBH + bh) * 64;
        #pragma unroll
        for (int mi = 0; mi < 4; ++mi)
            #pragma unroll
            for (int r = 0; r < 4; ++r)
                kp[mi * 16 + lk * 4 + r] = kacc[mi][r];
    }
}

// ---------------- reduce: sum partials; emit ctxT hi/lo bf16 [bh][e][d] + kc fp32 ----------------
__global__ __launch_bounds__(256) void reduce_kernel(const float* __restrict__ ctxP,
                                                     const float* __restrict__ kcP,
                                                     unsigned short* __restrict__ cTh,
                                                     unsigned short* __restrict__ cTl,
                                                     float* __restrict__ kcR) {
    const int bh = blockIdx.x;
    const int t = threadIdx.x;
    #pragma unroll
    for (int p = 0; p < 4; ++p) {
        int idx = p * 256 + t;                            // f32x4 index; elems [d][e0..e0+3]
        f32x4 s = {0.f, 0.f, 0.f, 0.f};
        for (int c = 0; c < NCHUNK; ++c)
            s += ((const f32x4*)(ctxP + ((size_t)c * NBH + bh) * 4096))[idx];
        int d = idx >> 4, e0 = (idx & 15) * 4;
        #pragma unroll
        for (int j = 0; j < 4; ++j) {
            unsigned short hi = f2b(s[j]);
            cTh[(size_t)bh * 4096 + (e0 + j) * 64 + d] = hi;
            cTl[(size_t)bh * 4096 + (e0 + j) * 64 + d] = f2b(s[j] - b2f(hi));
        }
    }
    if (t < 64) {
        float s = 0.f;
        for (int c = 0; c < NCHUNK; ++c) s += kcP[((size_t)c * NBH + bh) * 64 + t];
        kcR[bh * 64 + t] = s;
    }
}

// ---------------- attn (MFMA): inner[n][h*64+e] = (q @ (ctx_hi+ctx_lo)) / (q . kc) ----------------
__global__ __launch_bounds__(256) void attn_kernel(const unsigned short* __restrict__ qF,
                                                   const unsigned short* __restrict__ cTh,
                                                   const unsigned short* __restrict__ cTl,
                                                   const float* __restrict__ kcR,
                                                   unsigned short* __restrict__ inner) {
    const int bh = blockIdx.x >> 6;
    const int rt = blockIdx.x & 63;
    const int b = bh >> 3, h = bh & 7;
    const size_t rowBase = (size_t)b * SEQ + (size_t)rt * 64;
    __shared__ __align__(16) unsigned short qs[64 * 64];
    __shared__ __align__(16) unsigned short chs[64 * 64];
    __shared__ __align__(16) unsigned short cls[64 * 64];
    __shared__ float dpart[64][4];
    __shared__ float dens[64];
    __shared__ float kcs[64];
    const int tid = threadIdx.x;
    const int lane = tid & 63, wv = tid >> 6;
    const int lr = lane & 15, lk = lane >> 4;
    const int xorv = (lr & 7) << 4;
    const int r_s = tid >> 3, s_s = tid & 7;

    #pragma unroll
    for (int j = 0; j < 2; ++j) {
        int r = j * 32 + r_s;
        int sc = (s_s ^ (r & 7)) << 3;
        gload16(qF + (rowBase + r) * DMODEL + h * 64 + sc, qs + (j * 256 + (wv << 6)) * 8);
        gload16(cTh + (size_t)bh * 4096 + r * 64 + sc, chs + (j * 256 + (wv << 6)) * 8);
        gload16(cTl + (size_t)bh * 4096 + r * 64 + sc, cls + (j * 256 + (wv << 6)) * 8);
    }
    if (tid < 64) kcs[tid] = kcR[bh * 64 + tid];
    __syncthreads();                                      // drain gload16 + kcs
    {   // denom partials: 4 d-quarters x 64 rows in parallel
        int row = tid & 63, part = tid >> 6;
        float s = 0.f;
        #pragma unroll
        for (int i = 0; i < 16; ++i) {
            int d = part * 16 + i;
            unsigned short qv = *(const unsigned short*)((const char*)qs + row * 128 + ((d * 2) ^ ((row & 7) << 4)));
            s += b2f(qv) * kcs[d];
        }
        dpart[row][part] = s;
    }
    __syncthreads();
    if (tid < 64) dens[tid] = 1e-8f + dpart[tid][0] + dpart[tid][1] + dpart[tid][2] + dpart[tid][3];
    __syncthreads();

    f32x4 acc[4] = {};
    #pragma unroll
    for (int kk = 0; kk < 2; ++kk) {
        bf16x8 af = *(const bf16x8*)((const char*)qs + (wv * 16 + lr) * 128 + ((kk * 64 + lk * 16) ^ xorv));
        #pragma unroll
        for (int ni = 0; ni < 4; ++ni) {
            bf16x8 bh_ = *(const bf16x8*)((const char*)chs + (ni * 16 + lr) * 128 + ((kk * 64 + lk * 16) ^ xorv));
            bf16x8 bl_ = *(const bf16x8*)((const char*)cls + (ni * 16 + lr) * 128 + ((kk * 64 + lk * 16) ^ xorv));
            acc[ni] = __builtin_amdgcn_mfma_f32_16x16x32_bf16(af, bh_, acc[ni], 0, 0, 0);
            acc[ni] = __builtin_amdgcn_mfma_f32_16x16x32_bf16(af, bl_, acc[ni], 0, 0, 0);
        }
    }
    #pragma unroll
    for (int ni = 0; ni < 4; ++ni)
        #pragma unroll
        for (int r = 0; r < 4; ++r) {
            int n = wv * 16 + lk * 4 + r;
            float o = acc[ni][r] / dens[n];
            inner[(rowBase + n) * DMODEL + h * 64 + ni * 16 + lr] = f2b(o);
        }
}

extern "C" void kernel_launch(void* const* d_in, const int* in_sizes, int n_in,
                              void* d_out, int out_size, void* d_ws, size_t ws_size,
                              hipStream_t stream) {
    (void)in_sizes; (void)n_in; (void)out_size; (void)ws_size;
    const float* x    = (const float*)d_in[0];
    const float* wqkv = (const float*)d_in[1];
    const float* wout = (const float*)d_in[2];
    const float* bout = (const float*)d_in[3];

    char* w = (char*)d_ws;
    // Region [0, 32MB): xB (prep->gemm0), then ctxP+kcP (ctx->reduce), then inner (attn->gemm1)
    unsigned short* xB    = (unsigned short*)(w);                 // 32768*512*2  = 33554432
    float*          ctxP  = (float*)(w);                          // 8*64*4096*4  = 8388608
    float*          kcP   = (float*)(w + 8388608);                // 8*64*64*4    = 131072
    unsigned short* inner = (unsigned short*)(w);                 // 33554432
    unsigned short* qF    = (unsigned short*)(w + 33554432);      // 32768*512*2  = 33554432
    unsigned short* kT    = (unsigned short*)(w + 67108864);      // 64*64*4096*2 = 33554432
    unsigned short* vT    = (unsigned short*)(w + 100663296);     // 33554432
    unsigned short* wqkvB = (unsigned short*)(w + 134217728);     // 1536*512*2 = 1572864
    unsigned short* woutB = (unsigned short*)(w + 135790592);     // 512*512*2  = 524288
    unsigned short* cTh   = (unsigned short*)(w + 136314880);     // 64*64*64*2   = 524288
    unsigned short* cTl   = (unsigned short*)(w + 136839168);     // 524288
    float*          kcR   = (float*)(w + 137363456);              // 64*64*4      = 16384
    // total ws usage: 137379840 bytes (< 144834560 proven available)

    hipLaunchKernelGGL(prep_kernel, dim3(2048), dim3(256), 0, stream,
                       x, wqkv, wout, xB, wqkvB, woutB);
    hipLaunchKernelGGL((gemm_kernel<0>), dim3(768), dim3(512), 0, stream,
                       xB, wqkvB, (void*)qF, kT, vT, (const float*)nullptr,
                       NTOK, NQKV, DMODEL, 6);
    hipLaunchKernelGGL(ctx_kernel, dim3(NBH * NCHUNK), dim3(256), 0, stream, kT, vT, ctxP, kcP);
    hipLaunchKernelGGL(reduce_kernel, dim3(NBH), dim3(256), 0, stream, ctxP, kcP, cTh, cTl, kcR);
    hipLaunchKernelGGL(attn_kernel, dim3(NBH * 64), dim3(256), 0, stream, qF, cTh, cTl, kcR, inner);
    hipLaunchKernelGGL((gemm_kernel<1>), dim3(256), dim3(512), 0, stream,
                       inner, woutB, (void*)d_out, (unsigned short*)nullptr, (unsigned short*)nullptr, bout,
                       NTOK, DMODEL, DMODEL, 2);
}

// Round 12
// 156.069 us; speedup vs baseline: 2.0554x; 1.0210x over previous
//
#include <hip/hip_runtime.h>
#include <cstdint>
#include <cstddef>

typedef __bf16 bf16_t;
typedef bf16_t bf16x8 __attribute__((ext_vector_type(8)));
typedef float f32x4 __attribute__((ext_vector_type(4)));
typedef unsigned short u16x8 __attribute__((ext_vector_type(8)));
typedef unsigned short u16x4 __attribute__((ext_vector_type(4)));

#define SEQ 4096
#define BATCH 8
#define NTOK 32768      // BATCH*SEQ
#define NQKV 1536
#define DMODEL 512
#define NBH 64          // BATCH*HEADS
#define NCHUNK 8

__device__ __forceinline__ unsigned short f2b(float f) {
    union { float f; unsigned u; } c; c.f = f;
    unsigned u = c.u;
    u += 0x7fffu + ((u >> 16) & 1u);   // round-to-nearest-even
    return (unsigned short)(u >> 16);
}
__device__ __forceinline__ float b2f(unsigned short h) {
    union { unsigned u; float f; } c; c.u = ((unsigned)h) << 16;
    return c.f;
}
__device__ __forceinline__ float feat(float v) {   // elu(v)+1
    return v > 0.f ? v + 1.f : __expf(v);
}

// async global->LDS, 16B per lane; LDS dest is wave-uniform base + lane*16
__device__ __forceinline__ void gload16(const unsigned short* g, unsigned short* lds_base) {
    __builtin_amdgcn_global_load_lds((const __attribute__((address_space(1))) unsigned int*)g,
                                     (__attribute__((address_space(3))) unsigned int*)lds_base,
                                     16, 0, 0);
}

// ---------------- prep: fp32 -> bf16 for x and both weights ----------------
__global__ __launch_bounds__(256) void prep_kernel(const float* __restrict__ x,
                                                   const float* __restrict__ wqkv,
                                                   const float* __restrict__ wout,
                                                   unsigned short* __restrict__ xB,
                                                   unsigned short* __restrict__ wqkvB,
                                                   unsigned short* __restrict__ woutB) {
    const int stride = gridDim.x * 256;
    const int t0 = blockIdx.x * 256 + threadIdx.x;
    for (int j = t0; j < NTOK * DMODEL / 4; j += stride) {
        f32x4 v = ((const f32x4*)x)[j];
        u16x4 o = { f2b(v[0]), f2b(v[1]), f2b(v[2]), f2b(v[3]) };
        ((u16x4*)xB)[j] = o;
    }
    for (int j = t0; j < NQKV * DMODEL / 4; j += stride) {
        f32x4 v = ((const f32x4*)wqkv)[j];
        u16x4 o = { f2b(v[0]), f2b(v[1]), f2b(v[2]), f2b(v[3]) };
        ((u16x4*)wqkvB)[j] = o;
    }
    for (int j = t0; j < DMODEL * DMODEL / 4; j += stride) {
        f32x4 v = ((const f32x4*)wout)[j];
        u16x4 o = { f2b(v[0]), f2b(v[1]), f2b(v[2]), f2b(v[3]) };
        ((u16x4*)woutB)[j] = o;
    }
}

// ---------------- MFMA GEMM: C = A @ B^T, A bf16 [M][K], B bf16 [N][K] ----------------
// 256x256 tile, 16 waves (4M x 4N; wave = 64x64, acc[4][4] -- R7's proven low-pressure
// per-wave profile), BK=64. Single-buffer LDS (A 32K + B 32K), two __syncthreads/step.
// 2 blocks/CU -> 32 waves/CU (full occupancy): tests the latency-hiding hypothesis.
// gload16 staging + T2 XOR-swizzle (0 conflicts), T1 XCD swizzle.
// MODE 0: feature-map epilogue -> qF [tok][512] bf16; kT/vT [bh][d][4096] bf16 (transposed)
// MODE 1: +bias epilogue -> fp32 out [tok][512]   (Ck/Cv unused)
template <int MODE>
__global__ __launch_bounds__(1024) void gemm_kernel(const unsigned short* __restrict__ A,
                                                    const unsigned short* __restrict__ B,
                                                    void* __restrict__ Cq,
                                                    unsigned short* __restrict__ Ck,
                                                    unsigned short* __restrict__ Cv,
                                                    const float* __restrict__ bias,
                                                    int M, int N, int K, int nColBlocks) {
    __shared__ __align__(16) unsigned short As_[256 * 64];   // 32 KiB
    __shared__ __align__(16) unsigned short Bs_[256 * 64];   // 32 KiB
    const int tid = threadIdx.x;
    const int nwg = gridDim.x;
    int bid = blockIdx.x;
    if ((nwg & 7) == 0) bid = (bid & 7) * (nwg >> 3) + (bid >> 3);
    const int brow = bid / nColBlocks, bcol = bid % nColBlocks;
    const int rowBase = brow * 256, colBase = bcol * 256;
    const int lane = tid & 63, wv = tid >> 6;      // 16 waves
    const int wm = wv >> 2, wn = wv & 3;           // 4M x 4N (wave = 64x64 output)
    const int lr = lane & 15, lk = lane >> 4;
    const int sr = tid >> 3;                       // staging row within 128-row round
    const int ss = tid & 7;                        // staging slot

    f32x4 acc[4][4] = {};

    for (int kt = 0; kt < K; kt += 64) {
        // ---- stage A 256x64 (2 rounds) + B 256x64 (2 rounds), pre-swizzled source ----
        #pragma unroll
        for (int j = 0; j < 2; ++j) {
            int r = j * 128 + sr;
            int scol = ((ss ^ (r & 7)) << 3) + kt;
            gload16(A + (size_t)(rowBase + r) * K + scol, As_ + (j * 128 + (wv << 3)) * 64);
        }
        #pragma unroll
        for (int j = 0; j < 2; ++j) {
            int r = j * 128 + sr;
            int scol = ((ss ^ (r & 7)) << 3) + kt;
            gload16(B + (size_t)(colBase + r) * K + scol, Bs_ + (j * 128 + (wv << 3)) * 64);
        }
        __syncthreads();   // vmcnt(0) drain at barrier
        #pragma unroll
        for (int kk = 0; kk < 2; ++kk) {
            bf16x8 af[4], bfr[4];
            #pragma unroll
            for (int mi = 0; mi < 4; ++mi) {
                int row = wm * 64 + mi * 16 + lr;
                af[mi] = *(const bf16x8*)((const char*)As_ + row * 128 +
                                          ((kk * 64 + lk * 16) ^ ((row & 7) << 4)));
            }
            #pragma unroll
            for (int ni = 0; ni < 4; ++ni) {
                int row = wn * 64 + ni * 16 + lr;
                bfr[ni] = *(const bf16x8*)((const char*)Bs_ + row * 128 +
                                           ((kk * 64 + lk * 16) ^ ((row & 7) << 4)));
            }
            #pragma unroll
            for (int mi = 0; mi < 4; ++mi)
                #pragma unroll
                for (int ni = 0; ni < 4; ++ni)
                    acc[mi][ni] = __builtin_amdgcn_mfma_f32_16x16x32_bf16(af[mi], bfr[ni], acc[mi][ni], 0, 0, 0);
        }
        __syncthreads();   // protect LDS before next-step staging
    }

    // ---- epilogue: C/D layout col=lane&15, row=(lane>>4)*4+reg ----
    // colSeg uniform per wave; 256-col blocks never straddle q/k/v boundaries.
    const int colSeg = colBase + wn * 64;
    if (MODE == 1) {
        #pragma unroll
        for (int mi = 0; mi < 4; ++mi) {
            const int grow0 = rowBase + wm * 64 + mi * 16 + lk * 4;
            #pragma unroll
            for (int ni = 0; ni < 4; ++ni) {
                const int gcol = colSeg + ni * 16 + lr;
                #pragma unroll
                for (int r = 0; r < 4; ++r)
                    ((float*)Cq)[(size_t)(grow0 + r) * DMODEL + gcol] = acc[mi][ni][r] + bias[gcol];
            }
        }
    } else if (colSeg < 512) {            // q: elu(q*scale)+1, row-major [tok][512]
        #pragma unroll
        for (int mi = 0; mi < 4; ++mi) {
            const int grow0 = rowBase + wm * 64 + mi * 16 + lk * 4;
            #pragma unroll
            for (int ni = 0; ni < 4; ++ni) {
                const int gcol = colSeg + ni * 16 + lr;
                #pragma unroll
                for (int r = 0; r < 4; ++r)
                    ((unsigned short*)Cq)[(size_t)(grow0 + r) * DMODEL + gcol] =
                        f2b(feat(acc[mi][ni][r] * 0.125f));
            }
        }
    } else if (colSeg < 1024) {           // k: elu(k)+1 -> kT [bh*64+d][n]
        #pragma unroll
        for (int mi = 0; mi < 4; ++mi) {
            const int grow0 = rowBase + wm * 64 + mi * 16 + lk * 4;
            const int b_ = grow0 >> 12, n0 = grow0 & 4095;
            #pragma unroll
            for (int ni = 0; ni < 4; ++ni) {
                const int hd = colSeg - 512 + ni * 16 + lr;
                u16x4 o = { f2b(feat(acc[mi][ni][0])), f2b(feat(acc[mi][ni][1])),
                            f2b(feat(acc[mi][ni][2])), f2b(feat(acc[mi][ni][3])) };
                *(u16x4*)&Ck[((size_t)(b_ * 512 + hd)) * SEQ + n0] = o;
            }
        }
    } else {                              // v raw -> vT [bh*64+d][n]
        #pragma unroll
        for (int mi = 0; mi < 4; ++mi) {
            const int grow0 = rowBase + wm * 64 + mi * 16 + lk * 4;
            const int b_ = grow0 >> 12, n0 = grow0 & 4095;
            #pragma unroll
            for (int ni = 0; ni < 4; ++ni) {
                const int hd = colSeg - 1024 + ni * 16 + lr;
                u16x4 o = { f2b(acc[mi][ni][0]), f2b(acc[mi][ni][1]),
                            f2b(acc[mi][ni][2]), f2b(acc[mi][ni][3]) };
                *(u16x4*)&Cv[((size_t)(b_ * 512 + hd)) * SEQ + n0] = o;
            }
        }
    }
}

// ---------------- ctx (MFMA): ctxP[chunk][bh][d][e] = sum_n k[n][d] v[n][e]; kc via ones ----
__global__ __launch_bounds__(256) void ctx_kernel(const unsigned short* __restrict__ kT,
                                                  const unsigned short* __restrict__ vT,
                                                  float* __restrict__ ctxP,
                                                  float* __restrict__ kcP) {
    const int bh = blockIdx.x >> 3;
    const int chunk = blockIdx.x & 7;
    __shared__ __align__(16) unsigned short ks[64 * 64];
    __shared__ __align__(16) unsigned short vs[64 * 64];
    const int tid = threadIdx.x;
    const int lane = tid & 63, wv = tid >> 6;
    const int lr = lane & 15, lk = lane >> 4;
    const int xorv = (lr & 7) << 4;
    const int r_s = tid >> 3, s_s = tid & 7;
    const unsigned short* kg = kT + (size_t)bh * 64 * SEQ;
    const unsigned short* vg = vT + (size_t)bh * 64 * SEQ;

    f32x4 acc[4] = {};
    f32x4 kacc[4] = {};
    union { u16x8 u; bf16x8 b; } onesc;
    onesc.u = (u16x8){0x3F80, 0x3F80, 0x3F80, 0x3F80, 0x3F80, 0x3F80, 0x3F80, 0x3F80};
    const bf16x8 ones = onesc.b;

    for (int t = 0; t < 8; ++t) {
        const int n0 = chunk * 512 + t * 64;
        __syncthreads();                                  // protect prev-tile reads
        #pragma unroll
        for (int j = 0; j < 2; ++j) {
            int r = j * 32 + r_s;                         // d-row 0..63
            int scol = ((s_s ^ (r & 7)) << 3) + n0;       // pre-swizzled source
            gload16(kg + (size_t)r * SEQ + scol, ks + (j * 256 + (wv << 6)) * 8);
            gload16(vg + (size_t)r * SEQ + scol, vs + (j * 256 + (wv << 6)) * 8);
        }
        __syncthreads();                                  // drain gload16
        #pragma unroll
        for (int kk = 0; kk < 2; ++kk) {
            bf16x8 bfr = *(const bf16x8*)((const char*)vs + (wv * 16 + lr) * 128 + ((kk * 64 + lk * 16) ^ xorv));
            #pragma unroll
            for (int mi = 0; mi < 4; ++mi) {
                bf16x8 af = *(const bf16x8*)((const char*)ks + (mi * 16 + lr) * 128 + ((kk * 64 + lk * 16) ^ xorv));
                acc[mi] = __builtin_amdgcn_mfma_f32_16x16x32_bf16(af, bfr, acc[mi], 0, 0, 0);
                if (wv == 0)
                    kacc[mi] = __builtin_amdgcn_mfma_f32_16x16x32_bf16(af, ones, kacc[mi], 0, 0, 0);
            }
        }
    }
    float* cp = ctxP + ((size_t)chunk * NBH + bh) * 4096;
    #pragma unroll
    for (int mi = 0; mi < 4; ++mi)
        #pragma unroll
        for (int r = 0; r < 4; ++r)
            cp[(mi * 16 + lk * 4 + r) * 64 + wv * 16 + lr] = acc[mi][r];
    if (wv == 0 && lr == 0) {
        float* kp = kcP + ((size_t)chunk * NBH + bh) * 64;
        #pragma unroll
        for (int mi = 0; mi < 4; ++mi)
            #pragma unroll
            for (int r = 0; r < 4; ++r)
                kp[mi * 16 + lk * 4 + r] = kacc[mi][r];
    }
}

// ---------------- reduce: sum partials; emit ctxT hi/lo bf16 [bh][e][d] + kc fp32 ----------------
__global__ __launch_bounds__(256) void reduce_kernel(const float* __restrict__ ctxP,
                                                     const float* __restrict__ kcP,
                                                     unsigned short* __restrict__ cTh,
                                                     unsigned short* __restrict__ cTl,
                                                     float* __restrict__ kcR) {
    const int bh = blockIdx.x;
    const int t = threadIdx.x;
    #pragma unroll
    for (int p = 0; p < 4; ++p) {
        int idx = p * 256 + t;                            // f32x4 index; elems [d][e0..e0+3]
        f32x4 s = {0.f, 0.f, 0.f, 0.f};
        for (int c = 0; c < NCHUNK; ++c)
            s += ((const f32x4*)(ctxP + ((size_t)c * NBH + bh) * 4096))[idx];
        int d = idx >> 4, e0 = (idx & 15) * 4;
        #pragma unroll
        for (int j = 0; j < 4; ++j) {
            unsigned short hi = f2b(s[j]);
            cTh[(size_t)bh * 4096 + (e0 + j) * 64 + d] = hi;
            cTl[(size_t)bh * 4096 + (e0 + j) * 64 + d] = f2b(s[j] - b2f(hi));
        }
    }
    if (t < 64) {
        float s = 0.f;
        for (int c = 0; c < NCHUNK; ++c) s += kcP[((size_t)c * NBH + bh) * 64 + t];
        kcR[bh * 64 + t] = s;
    }
}

// ---------------- attn (MFMA): inner[n][h*64+e] = (q @ (ctx_hi+ctx_lo)) / (q . kc) ----------------
__global__ __launch_bounds__(256) void attn_kernel(const unsigned short* __restrict__ qF,
                                                   const unsigned short* __restrict__ cTh,
                                                   const unsigned short* __restrict__ cTl,
                                                   const float* __restrict__ kcR,
                                                   unsigned short* __restrict__ inner) {
    const int bh = blockIdx.x >> 6;
    const int rt = blockIdx.x & 63;
    const int b = bh >> 3, h = bh & 7;
    const size_t rowBase = (size_t)b * SEQ + (size_t)rt * 64;
    __shared__ __align__(16) unsigned short qs[64 * 64];
    __shared__ __align__(16) unsigned short chs[64 * 64];
    __shared__ __align__(16) unsigned short cls[64 * 64];
    __shared__ float dpart[64][4];
    __shared__ float dens[64];
    __shared__ float kcs[64];
    const int tid = threadIdx.x;
    const int lane = tid & 63, wv = tid >> 6;
    const int lr = lane & 15, lk = lane >> 4;
    const int xorv = (lr & 7) << 4;
    const int r_s = tid >> 3, s_s = tid & 7;

    #pragma unroll
    for (int j = 0; j < 2; ++j) {
        int r = j * 32 + r_s;
        int sc = (s_s ^ (r & 7)) << 3;
        gload16(qF + (rowBase + r) * DMODEL + h * 64 + sc, qs + (j * 256 + (wv << 6)) * 8);
        gload16(cTh + (size_t)bh * 4096 + r * 64 + sc, chs + (j * 256 + (wv << 6)) * 8);
        gload16(cTl + (size_t)bh * 4096 + r * 64 + sc, cls + (j * 256 + (wv << 6)) * 8);
    }
    if (tid < 64) kcs[tid] = kcR[bh * 64 + tid];
    __syncthreads();                                      // drain gload16 + kcs
    {   // denom partials: 4 d-quarters x 64 rows in parallel
        int row = tid & 63, part = tid >> 6;
        float s = 0.f;
        #pragma unroll
        for (int i = 0; i < 16; ++i) {
            int d = part * 16 + i;
            unsigned short qv = *(const unsigned short*)((const char*)qs + row * 128 + ((d * 2) ^ ((row & 7) << 4)));
            s += b2f(qv) * kcs[d];
        }
        dpart[row][part] = s;
    }
    __syncthreads();
    if (tid < 64) dens[tid] = 1e-8f + dpart[tid][0] + dpart[tid][1] + dpart[tid][2] + dpart[tid][3];
    __syncthreads();

    f32x4 acc[4] = {};
    #pragma unroll
    for (int kk = 0; kk < 2; ++kk) {
        bf16x8 af = *(const bf16x8*)((const char*)qs + (wv * 16 + lr) * 128 + ((kk * 64 + lk * 16) ^ xorv));
        #pragma unroll
        for (int ni = 0; ni < 4; ++ni) {
            bf16x8 bh_ = *(const bf16x8*)((const char*)chs + (ni * 16 + lr) * 128 + ((kk * 64 + lk * 16) ^ xorv));
            bf16x8 bl_ = *(const bf16x8*)((const char*)cls + (ni * 16 + lr) * 128 + ((kk * 64 + lk * 16) ^ xorv));
            acc[ni] = __builtin_amdgcn_mfma_f32_16x16x32_bf16(af, bh_, acc[ni], 0, 0, 0);
            acc[ni] = __builtin_amdgcn_mfma_f32_16x16x32_bf16(af, bl_, acc[ni], 0, 0, 0);
        }
    }
    #pragma unroll
    for (int ni = 0; ni < 4; ++ni)
        #pragma unroll
        for (int r = 0; r < 4; ++r) {
            int n = wv * 16 + lk * 4 + r;
            float o = acc[ni][r] / dens[n];
            inner[(rowBase + n) * DMODEL + h * 64 + ni * 16 + lr] = f2b(o);
        }
}

extern "C" void kernel_launch(void* const* d_in, const int* in_sizes, int n_in,
                              void* d_out, int out_size, void* d_ws, size_t ws_size,
                              hipStream_t stream) {
    (void)in_sizes; (void)n_in; (void)out_size; (void)ws_size;
    const float* x    = (const float*)d_in[0];
    const float* wqkv = (const float*)d_in[1];
    const float* wout = (const float*)d_in[2];
    const float* bout = (const float*)d_in[3];

    char* w = (char*)d_ws;
    // Region [0, 32MB): xB (prep->gemm0), then ctxP+kcP (ctx->reduce), then inner (attn->gemm1)
    unsigned short* xB    = (unsigned short*)(w);                 // 32768*512*2  = 33554432
    float*          ctxP  = (float*)(w);                          // 8*64*4096*4  = 8388608
    float*          kcP   = (float*)(w + 8388608);                // 8*64*64*4    = 131072
    unsigned short* inner = (unsigned short*)(w);                 // 33554432
    unsigned short* qF    = (unsigned short*)(w + 33554432);      // 32768*512*2  = 33554432
    unsigned short* kT    = (unsigned short*)(w + 67108864);      // 64*64*4096*2 = 33554432
    unsigned short* vT    = (unsigned short*)(w + 100663296);     // 33554432
    unsigned short* wqkvB = (unsigned short*)(w + 134217728);     // 1536*512*2 = 1572864
    unsigned short* woutB = (unsigned short*)(w + 135790592);     // 512*512*2  = 524288
    unsigned short* cTh   = (unsigned short*)(w + 136314880);     // 64*64*64*2   = 524288
    unsigned short* cTl   = (unsigned short*)(w + 136839168);     // 524288
    float*          kcR   = (float*)(w + 137363456);              // 64*64*4      = 16384
    // total ws usage: 137379840 bytes (< 144834560 proven available)

    hipLaunchKernelGGL(prep_kernel, dim3(2048), dim3(256), 0, stream,
                       x, wqkv, wout, xB, wqkvB, woutB);
    hipLaunchKernelGGL((gemm_kernel<0>), dim3(768), dim3(1024), 0, stream,
                       xB, wqkvB, (void*)qF, kT, vT, (const float*)nullptr,
                       NTOK, NQKV, DMODEL, 6);
    hipLaunchKernelGGL(ctx_kernel, dim3(NBH * NCHUNK), dim3(256), 0, stream, kT, vT, ctxP, kcP);
    hipLaunchKernelGGL(reduce_kernel, dim3(NBH), dim3(256), 0, stream, ctxP, kcP, cTh, cTl, kcR);
    hipLaunchKernelGGL(attn_kernel, dim3(NBH * 64), dim3(256), 0, stream, qF, cTh, cTl, kcR, inner);
    hipLaunchKernelGGL((gemm_kernel<1>), dim3(256), dim3(1024), 0, stream,
                       inner, woutB, (void*)d_out, (unsigned short*)nullptr, (unsigned short*)nullptr, bout,
                       NTOK, DMODEL, DMODEL, 2);
}